// Round 10
// baseline (2287.423 us; speedup 1.0000x reference)
//
#include <hip/hip_runtime.h>

// AttentionBlock: GN(32) -> q,k,v 1x1 -> softmax(qk^T/sqrt(C)) v -> proj + residual
// B=8, C=512, N=4096. ALL GEMMs on gemm256 (256x256 8-phase counted-vmcnt).
// Round 10: template<EPI,BK>. BK=32 (64 KiB LDS -> 2 blocks/CU) for the short-K
// fat-M GEMMs (QK^T, QKfused) so a second independent block hides per-phase
// barrier stalls; BK=64 path byte-identical to round 9 for PV/projections.

typedef __attribute__((ext_vector_type(8))) __bf16 bf16x8;
typedef __attribute__((ext_vector_type(4))) float f32x4;
typedef unsigned int u32;

#define DEVICE __device__ __forceinline__

DEVICE void async_copy16(const void* g, void* l) {
  __builtin_amdgcn_global_load_lds(
      (__attribute__((address_space(1))) u32*)(g),
      (__attribute__((address_space(3))) u32*)(l),
      16, 0, 0);
}

template <int BK>
DEVICE void wait_steady() {
  if constexpr (BK == 64)
    asm volatile("s_waitcnt vmcnt(4)" ::: "memory");
  else
    asm volatile("s_waitcnt vmcnt(2)" ::: "memory");
}

// ---------------------------------------------------------------- weights->bf16
__global__ __launch_bounds__(256) void cvt_w(
    const float* __restrict__ w0, const float* __restrict__ w1,
    const float* __restrict__ w2, const float* __restrict__ w3,
    __bf16* __restrict__ o0, __bf16* __restrict__ o1,
    __bf16* __restrict__ o2, __bf16* __restrict__ o3) {
  int idx = blockIdx.x * 256 + threadIdx.x;
  int off = idx * 8;
  int m = off >> 18;
  int r = off & 262143;
  const float* src = m == 0 ? w0 : m == 1 ? w1 : m == 2 ? w2 : w3;
  __bf16* dst = m == 0 ? o0 : m == 1 ? o1 : m == 2 ? o2 : o3;
  float4 a = *(const float4*)(src + r);
  float4 b = *(const float4*)(src + r + 4);
  bf16x8 v = {(__bf16)a.x, (__bf16)a.y, (__bf16)a.z, (__bf16)a.w,
              (__bf16)b.x, (__bf16)b.y, (__bf16)b.z, (__bf16)b.w};
  *(bf16x8*)(dst + r) = v;
}

// ---------------------------------------------------------------- groupnorm partial stats
__global__ __launch_bounds__(256) void gn_stats(const float* __restrict__ x,
                                                float* __restrict__ stats4) {
  int bg = blockIdx.x, qn = blockIdx.y;
  int t = threadIdx.x, lane = t & 63, w = t >> 6;
  float s = 0.f, ss = 0.f;
  for (int it = 0; it < 16; ++it) {
    int idx = it * 256 + t;
    int ch = idx >> 8, f4 = idx & 255;
    float4 v = *(const float4*)(x + (size_t)bg * 65536 + (size_t)ch * 4096 +
                                qn * 1024 + f4 * 4);
    s += v.x + v.y + v.z + v.w;
    ss += v.x * v.x + v.y * v.y + v.z * v.z + v.w * v.w;
  }
#pragma unroll
  for (int off = 32; off; off >>= 1) {
    s += __shfl_xor(s, off);
    ss += __shfl_xor(ss, off);
  }
  __shared__ float rs_[4], rss_[4];
  if (lane == 0) { rs_[w] = s; rss_[w] = ss; }
  __syncthreads();
  if (t == 0) {
    stats4[(bg * 4 + qn) * 2] = rs_[0] + rs_[1] + rs_[2] + rs_[3];
    stats4[(bg * 4 + qn) * 2 + 1] = rss_[0] + rss_[1] + rss_[2] + rss_[3];
  }
}

// ---------------------------------------------------------------- groupnorm apply
__global__ __launch_bounds__(256) void gn_apply(
    const float* __restrict__ x, const float* __restrict__ gamma,
    const float* __restrict__ beta, const float* __restrict__ stats4,
    __bf16* __restrict__ h) {
  int b = blockIdx.z, g4 = blockIdx.y;
  int n = blockIdx.x * 256 + threadIdx.x;
  float mean[4], rstd[4];
#pragma unroll
  for (int k = 0; k < 4; ++k) {
    int bg = b * 32 + g4 * 4 + k;
    float s = 0.f, ss = 0.f;
#pragma unroll
    for (int q = 0; q < 4; ++q) {
      s += stats4[(bg * 4 + q) * 2];
      ss += stats4[(bg * 4 + q) * 2 + 1];
    }
    float m = s * (1.0f / 65536.0f);
    mean[k] = m;
    rstd[k] = rsqrtf(ss * (1.0f / 65536.0f) - m * m + 1e-5f);
  }
  const float* px = x + ((size_t)b * 512 + g4 * 64) * 4096 + n;
  __bf16* dst = h + ((size_t)b * 4096 + n) * 512 + g4 * 64;
#pragma unroll
  for (int j4 = 0; j4 < 8; ++j4) {
    bf16x8 o;
#pragma unroll
    for (int e = 0; e < 8; ++e) {
      int c = j4 * 8 + e;
      int g = c >> 4;
      float v = px[(size_t)c * 4096];
      o[e] = (__bf16)((v - mean[g]) * rstd[g] * gamma[g4 * 64 + c] +
                      beta[g4 * 64 + c]);
    }
    *(bf16x8*)(dst + j4 * 8) = o;
  }
}

// ---------------------------------------------------------------- gemm256<EPI,BK>
// C[m,n] = sum_k A[m,k]*B[n,k]. 512 thr = 8 waves (2M x 4N), wave tile 128x64.
// BK=64: 128 KiB LDS, 1 blk/CU, XOR(row&7) swizzle, vmcnt(4). [round-9 path]
// BK=32: 64 KiB LDS, 2 blk/CU (cross-block overlap), natural layout is
//        conflict-free for b128 frag reads (no swizzle), vmcnt(2).
// EPI: 0 plain bf16 | 1 bf16 + 2-ptr colbias (QK fused) | 2 bf16 + rowbias (V)
//      3 f32 token-major: out[(row>>12)*512+col][row&4095] = acc+bias0[col]+resid

#define G256_PHASE(BUF, QR, QC, RDA, RDB, STAGE_STMT, TAIL_STMT)               \
  do {                                                                         \
    if (RDA) {                                                                 \
      _Pragma("unroll") for (int fr = 0; fr < 4; ++fr)                         \
          _Pragma("unroll") for (int kh = 0; kh < KH; ++kh)                    \
              a[fr][kh] = ldA(BUF, (QR)*4 + fr, kh);                           \
    }                                                                          \
    if (RDB) {                                                                 \
      _Pragma("unroll") for (int fc = 0; fc < 2; ++fc)                         \
          _Pragma("unroll") for (int kh = 0; kh < KH; ++kh)                    \
              b[(QC)*2 + fc][kh] = ldB(BUF, (QC)*2 + fc, kh);                  \
    }                                                                          \
    STAGE_STMT;                                                                \
    __builtin_amdgcn_s_barrier();                                              \
    asm volatile("s_waitcnt lgkmcnt(0)" ::: "memory");                         \
    __builtin_amdgcn_sched_barrier(0);                                         \
    __builtin_amdgcn_s_setprio(1);                                             \
    _Pragma("unroll") for (int fr = 0; fr < 4; ++fr)                           \
        _Pragma("unroll") for (int fc = 0; fc < 2; ++fc)                       \
            _Pragma("unroll") for (int kh = 0; kh < KH; ++kh)                  \
                acc[(QR)*4 + fr][(QC)*2 + fc] =                                \
                    __builtin_amdgcn_mfma_f32_16x16x32_bf16(                   \
                        a[fr][kh], b[(QC)*2 + fc][kh],                         \
                        acc[(QR)*4 + fr][(QC)*2 + fc], 0, 0, 0);               \
    __builtin_amdgcn_s_setprio(0);                                             \
    TAIL_STMT;                                                                 \
    __builtin_amdgcn_sched_barrier(0);                                         \
    __builtin_amdgcn_s_barrier();                                              \
  } while (0)

#define G256_ITER(T0, T1, LAST)                                                \
  G256_PHASE(0, 0, 0, 1, 1, stage(1, 0, 0, (T1)), ((void)0));                  \
  G256_PHASE(0, 0, 1, 0, 1, stage(1, 0, 1, (T1)), ((void)0));                  \
  G256_PHASE(0, 1, 0, 1, 0,                                                    \
             if (!(LAST)) stage(0, 1, 0, (T0) + 2), ((void)0));                \
  G256_PHASE(0, 1, 1, 0, 0,                                                    \
             if (!(LAST)) stage(0, 1, 1, (T0) + 2),                            \
             if (LAST) {                                                       \
               asm volatile("s_waitcnt vmcnt(0)" ::: "memory");                \
             } else {                                                          \
               wait_steady<BK>();                                              \
             });                                                               \
  G256_PHASE(1, 0, 0, 1, 1,                                                    \
             if (!(LAST)) stage(0, 0, 0, (T0) + 2), ((void)0));                \
  G256_PHASE(1, 0, 1, 0, 1,                                                    \
             if (!(LAST)) stage(0, 0, 1, (T0) + 2), ((void)0));                \
  G256_PHASE(1, 1, 0, 1, 0,                                                    \
             if (!(LAST)) stage(1, 1, 0, (T1) + 2), ((void)0));                \
  G256_PHASE(1, 1, 1, 0, 0,                                                    \
             if (!(LAST)) stage(1, 1, 1, (T1) + 2),                            \
             if (!(LAST)) { wait_steady<BK>(); })

template <int EPI, int BK>
__global__ __launch_bounds__(512, BK == 32 ? 4 : 2) void gemm256(
    const __bf16* __restrict__ A, const __bf16* __restrict__ B,
    void* __restrict__ CoutV, int lda, int ldb, int ldc, int nIter, int nTM,
    int nTN, int KS, long sA, long sKA, long sB, long sKB, long sC,
    const float* __restrict__ bias0, const float* __restrict__ bias1,
    const float* __restrict__ resid) {
  constexpr int KH = BK / 32;            // kh halves per phase
  constexpr int LPT = BK / 32;           // gload_lds per thread per stage
  constexpr int CPR = BK / 8;            // 16B chunks per row
  constexpr size_t HALF = (size_t)128 * BK * 2;  // bytes per half-tile
  __shared__ __bf16 lds_raw[2][2][2][128][BK];   // [buf][mat][half][row][k]

  int nwg = gridDim.x, bid = blockIdx.x;
  int qq = nwg >> 3, rr = nwg & 7;
  int xcd = bid & 7, ii = bid >> 3;
  int swz = (xcd < rr ? xcd * (qq + 1) : rr * (qq + 1) + (xcd - rr) * qq) + ii;
  int tn = swz % nTN;
  int tm = (swz / nTN) % nTM;
  int zz = swz / (nTN * nTM);
  int z = zz / KS, ks = zz % KS;
  A += (size_t)z * sA + (size_t)ks * sKA;
  B += (size_t)z * sB + (size_t)ks * sKB;
  __bf16* Cout = (__bf16*)CoutV + (size_t)zz * sC;
  int row0 = tm * 256, col0 = tn * 256;

  int tid = threadIdx.x;
  int wid = tid >> 6, lane = tid & 63;
  int wr = wid >> 2, wc = wid & 3;
  int l15 = lane & 15, l4 = lane >> 4;

  auto stage = [&](int buf, int mat, int half, int kt) {
    const __bf16* src = mat ? B : A;
    int ld = mat ? ldb : lda;
    int rbase = (mat ? col0 : row0) + half * 128;
    char* ldsbase = (char*)lds_raw + (((buf * 2 + mat) * 2 + half) * HALF);
#pragma unroll
    for (int L = 0; L < LPT; ++L) {
      int ci = L * 512 + wid * 64 + lane;
      int r = ci / CPR, cslot = ci % CPR;
      int csrc = (BK == 64) ? (cslot ^ (r & 7)) : cslot;
      async_copy16(src + (size_t)(rbase + r) * ld + kt * BK + csrc * 8,
                   ldsbase + (size_t)(L * 512 + wid * 64) * 16);
    }
  };
  auto ldA = [&](int buf, int fr, int kh) -> bf16x8 {
    int row = fr * 16 + l15;
    int g = kh * 4 + l4;
    int slot = (BK == 64) ? (g ^ (row & 7)) : g;
    char* base = (char*)lds_raw + (((buf * 2 + 0) * 2 + wr) * HALF);
    return *(const bf16x8*)(base + (size_t)row * (BK * 2) + slot * 16);
  };
  auto ldB = [&](int buf, int fc, int kh) -> bf16x8 {
    int row = (wc & 1) * 64 + fc * 16 + l15;
    int g = kh * 4 + l4;
    int slot = (BK == 64) ? (g ^ (row & 7)) : g;
    char* base = (char*)lds_raw + (((buf * 2 + 1) * 2 + (wc >> 1)) * HALF);
    return *(const bf16x8*)(base + (size_t)row * (BK * 2) + slot * 16);
  };

  f32x4 acc[8][4] = {};
  bf16x8 a[4][KH], b[4][KH];

  stage(0, 1, 0, 0);
  stage(0, 1, 1, 0);
  stage(0, 0, 0, 0);
  stage(0, 0, 1, 0);
  stage(1, 1, 0, 1);
  stage(1, 1, 1, 1);
  wait_steady<BK>();
  __builtin_amdgcn_sched_barrier(0);
  __builtin_amdgcn_s_barrier();

  int it = 0;
  for (; it < nIter - 1; ++it) {
    G256_ITER(2 * it, 2 * it + 1, 0);
  }
  G256_ITER(2 * it, 2 * it + 1, 1);

  // epilogue: C/D layout col=lane&15, row=(lane>>4)*4+rg [m89-verified]
  int rb = row0 + wr * 128, cb = col0 + wc * 64;
  if constexpr (EPI == 3) {
#pragma unroll
    for (int fc = 0; fc < 4; ++fc) {
      int col = cb + fc * 16 + l15;
      float bb = bias0[col];
#pragma unroll
      for (int fr = 0; fr < 8; ++fr) {
        int r0 = rb + fr * 16 + l4 * 4;
        size_t idx = ((size_t)(r0 >> 12) * 512 + col) * 4096 + (r0 & 4095);
        float4 rv = *(const float4*)(resid + idx);
        float4 ov = {acc[fr][fc][0] + bb + rv.x, acc[fr][fc][1] + bb + rv.y,
                     acc[fr][fc][2] + bb + rv.z, acc[fr][fc][3] + bb + rv.w};
        *(float4*)((float*)CoutV + idx) = ov;
      }
    }
  } else {
#pragma unroll
    for (int fr = 0; fr < 8; ++fr) {
#pragma unroll
      for (int rg = 0; rg < 4; ++rg) {
        int row = rb + fr * 16 + l4 * 4 + rg;
#pragma unroll
        for (int fc = 0; fc < 4; ++fc) {
          int col = cb + fc * 16 + l15;
          float v = acc[fr][fc][rg];
          if constexpr (EPI == 1) v += col < 512 ? bias0[col] : bias1[col - 512];
          if constexpr (EPI == 2) v += bias0[row];
          Cout[(size_t)row * ldc + col] = (__bf16)v;
        }
      }
    }
  }
}

// ---------------------------------------------------------------- row softmax, in-place bf16 S -> bf16 P
__global__ __launch_bounds__(256) void softmax_rows_bf16(__bf16* __restrict__ S) {
  int row = blockIdx.x;
  __bf16* p = S + (size_t)row * 4096;
  int t = threadIdx.x, lane = t & 63, w = t >> 6;
  const float c1 = 0.04419417382415922f * 1.4426950408889634f;
  bf16x8 v0 = *(const bf16x8*)(p + t * 16);
  bf16x8 v1 = *(const bf16x8*)(p + t * 16 + 8);
  float f[16];
  float mx = -3.4e38f;
#pragma unroll
  for (int i = 0; i < 8; ++i) { f[i] = (float)v0[i]; mx = fmaxf(mx, f[i]); }
#pragma unroll
  for (int i = 0; i < 8; ++i) { f[8 + i] = (float)v1[i]; mx = fmaxf(mx, f[8 + i]); }
#pragma unroll
  for (int off = 32; off; off >>= 1) mx = fmaxf(mx, __shfl_xor(mx, off));
  __shared__ float rm[4], rsum[4];
  if (lane == 0) rm[w] = mx;
  __syncthreads();
  float m = fmaxf(fmaxf(rm[0], rm[1]), fmaxf(rm[2], rm[3]));
  float s = 0.f;
#pragma unroll
  for (int i = 0; i < 16; ++i) {
    f[i] = exp2f((f[i] - m) * c1);
    s += f[i];
  }
#pragma unroll
  for (int off = 32; off; off >>= 1) s += __shfl_xor(s, off);
  if (lane == 0) rsum[w] = s;
  __syncthreads();
  float inv = 1.0f / (rsum[0] + rsum[1] + rsum[2] + rsum[3]);
  bf16x8 o0, o1;
#pragma unroll
  for (int i = 0; i < 8; ++i) o0[i] = (__bf16)(f[i] * inv);
#pragma unroll
  for (int i = 0; i < 8; ++i) o1[i] = (__bf16)(f[8 + i] * inv);
  *(bf16x8*)(p + t * 16) = o0;
  *(bf16x8*)(p + t * 16 + 8) = o1;
}

// ---------------------------------------------------------------- sum 4 K-split partials -> O
__global__ __launch_bounds__(256) void reduce4(const __bf16* __restrict__ part,
                                               __bf16* __restrict__ out) {
  int z = blockIdx.y;
  size_t e = ((size_t)blockIdx.x * 256 + threadIdx.x) * 8;
  const __bf16* p = part + (size_t)z * 4 * 2097152 + e;
  bf16x8 v0 = *(const bf16x8*)(p);
  bf16x8 v1 = *(const bf16x8*)(p + 2097152);
  bf16x8 v2 = *(const bf16x8*)(p + 2 * 2097152);
  bf16x8 v3 = *(const bf16x8*)(p + 3 * 2097152);
  bf16x8 o;
#pragma unroll
  for (int j = 0; j < 8; ++j)
    o[j] = (__bf16)((float)v0[j] + (float)v1[j] + (float)v2[j] + (float)v3[j]);
  *(bf16x8*)(out + (size_t)z * 2097152 + e) = o;
}

// ---------------------------------------------------------------- launch
extern "C" void kernel_launch(void* const* d_in, const int* in_sizes, int n_in,
                              void* d_out, int out_size, void* d_ws, size_t ws_size,
                              hipStream_t stream) {
  const float* x = (const float*)d_in[0];
  const float* gamma = (const float*)d_in[1];
  const float* beta = (const float*)d_in[2];
  const float* wq = (const float*)d_in[3];
  const float* bq = (const float*)d_in[4];
  const float* wk = (const float*)d_in[5];
  const float* bk = (const float*)d_in[6];
  const float* wv = (const float*)d_in[7];
  const float* bv = (const float*)d_in[8];
  const float* wp = (const float*)d_in[9];
  const float* bp = (const float*)d_in[10];

  char* p = (char*)d_ws;
  auto alloc = [&](size_t bytes) {
    char* r = p;
    p += (bytes + 255) & ~(size_t)255;
    return r;
  };
  float* stats4 = (float*)alloc(256 * 4 * 2 * 4);
  __bf16* wqkb = (__bf16*)alloc((size_t)1024 * 512 * 2);    // [Wq; Wk]
  __bf16* wvb = (__bf16*)alloc(512 * 512 * 2);
  __bf16* wpb = (__bf16*)alloc(512 * 512 * 2);
  __bf16* ho = (__bf16*)alloc((size_t)8 * 4096 * 512 * 2);  // h, later aliased as O
  __bf16* qk = (__bf16*)alloc((size_t)8 * 4096 * 1024 * 2); // [B*N, 1024] Q|K
  __bf16* vt = (__bf16*)alloc((size_t)8 * 512 * 4096 * 2);  // [B, C, N]

  const size_t SB = (size_t)4096 * 4096 * 2;
  const size_t PB = (size_t)4 * 4096 * 512 * 2;
  size_t used = (size_t)(p - (char*)d_ws);
  size_t freeb = (ws_size > used) ? ws_size - used : 0;
  int nb = (int)(freeb / (SB + PB));
  if (nb > 8) nb = 8;
  if (nb < 1) nb = 1;
  __bf16* s = (__bf16*)alloc(SB * nb);
  __bf16* pvp = (__bf16*)alloc(PB * nb);

  cvt_w<<<512, 256, 0, stream>>>(wq, wk, wv, wp, wqkb, wqkb + 262144, wvb, wpb);
  gn_stats<<<dim3(256, 4), 256, 0, stream>>>(x, stats4);
  gn_apply<<<dim3(16, 8, 8), 256, 0, stream>>>(x, gamma, beta, stats4, ho);

  // QK fused: [32768,1024] = h x [Wq;Wk]^T + colbias2. BK=32, nIter=8, grid 512
  gemm256<1, 32><<<dim3(512), 512, 0, stream>>>(
      ho, wqkb, qk, 512, 512, 1024, 8, 128, 4, 1, 0, 0, 0, 0, 0, bq, bk, nullptr);
  // Vt[b] = Wv h[b]^T + rowbias. BK=64, grid 256 (1 blk/CU)
  gemm256<2, 64><<<dim3(256), 512, 0, stream>>>(
      wvb, ho, vt, 512, 512, 4096, 4, 2, 16, 1, 0, 0, 2097152, 0, 2097152,
      bv, nullptr, nullptr);

  __bf16* o = ho;  // h dead after V proj -> O aliases it
  for (int b0 = 0; b0 < 8; b0 += nb) {
    int zb = (8 - b0 < nb) ? (8 - b0) : nb;
    // S = Q K^T. BK=32, nIter=8, grid zb*256 (2 blk/CU at zb=2)
    gemm256<0, 32><<<dim3(zb * 256), 512, 0, stream>>>(
        qk + (size_t)b0 * 4194304, qk + (size_t)b0 * 4194304 + 512, s, 1024,
        1024, 4096, 8, 16, 16, 1, 4194304, 0, 4194304, 0, 16777216,
        nullptr, nullptr, nullptr);
    softmax_rows_bf16<<<zb * 4096, 256, 0, stream>>>(s);
    // partial O = P V, K-split x4: BK=64, nIter=8, grid zb*128
    gemm256<0, 64><<<dim3(zb * 128), 512, 0, stream>>>(
        s, vt + (size_t)b0 * 2097152, pvp, 4096, 4096, 512, 8, 16, 2, 4,
        16777216, 1024, 2097152, 1024, 2097152, nullptr, nullptr, nullptr);
    reduce4<<<dim3(1024, zb), 256, 0, stream>>>(pvp, o + (size_t)b0 * 2097152);
  }
  // out[b,c,n] = x + O Wp^T + bp (token-major epilogue, float4 resid+store)
  gemm256<3, 64><<<dim3(256), 512, 0, stream>>>(
      o, wpb, d_out, 512, 512, 0, 4, 128, 2, 1, 0, 0, 0, 0, 0, bp, nullptr, x);
}

// Round 11
// 664.928 us; speedup vs baseline: 3.4401x; 3.4401x over previous
//
#include <hip/hip_runtime.h>

// AttentionBlock: GN(32) -> q,k,v 1x1 -> softmax(qk^T/sqrt(C)) v -> proj + residual
// B=8, C=512, N=4096. ALL GEMMs on gemm256 (256x256 8-phase counted-vmcnt, 8 waves,
// BK=64, T1+T2+T3+T4+T5) == round-9 path. Round 11: segment pairing (nseg) — one
// block computes nseg adjacent N-tiles with a CONTINUOUS staging pipeline and a
// mid-stream epilogue, so short-K GEMMs (QK^T, QKfused) run one 1-blk/CU round
// with 2x the K-loop depth instead of two fill/drain rounds.

typedef __attribute__((ext_vector_type(8))) __bf16 bf16x8;
typedef __attribute__((ext_vector_type(4))) float f32x4;
typedef unsigned int u32;

#define DEVICE __device__ __forceinline__

DEVICE void async_copy16(const void* g, void* l) {
  __builtin_amdgcn_global_load_lds(
      (__attribute__((address_space(1))) u32*)(g),
      (__attribute__((address_space(3))) u32*)(l),
      16, 0, 0);
}

// ---------------------------------------------------------------- weights->bf16
__global__ __launch_bounds__(256) void cvt_w(
    const float* __restrict__ w0, const float* __restrict__ w1,
    const float* __restrict__ w2, const float* __restrict__ w3,
    __bf16* __restrict__ o0, __bf16* __restrict__ o1,
    __bf16* __restrict__ o2, __bf16* __restrict__ o3) {
  int idx = blockIdx.x * 256 + threadIdx.x;
  int off = idx * 8;
  int m = off >> 18;
  int r = off & 262143;
  const float* src = m == 0 ? w0 : m == 1 ? w1 : m == 2 ? w2 : w3;
  __bf16* dst = m == 0 ? o0 : m == 1 ? o1 : m == 2 ? o2 : o3;
  float4 a = *(const float4*)(src + r);
  float4 b = *(const float4*)(src + r + 4);
  bf16x8 v = {(__bf16)a.x, (__bf16)a.y, (__bf16)a.z, (__bf16)a.w,
              (__bf16)b.x, (__bf16)b.y, (__bf16)b.z, (__bf16)b.w};
  *(bf16x8*)(dst + r) = v;
}

// ---------------------------------------------------------------- groupnorm partial stats
__global__ __launch_bounds__(256) void gn_stats(const float* __restrict__ x,
                                                float* __restrict__ stats4) {
  int bg = blockIdx.x, qn = blockIdx.y;
  int t = threadIdx.x, lane = t & 63, w = t >> 6;
  float s = 0.f, ss = 0.f;
  for (int it = 0; it < 16; ++it) {
    int idx = it * 256 + t;
    int ch = idx >> 8, f4 = idx & 255;
    float4 v = *(const float4*)(x + (size_t)bg * 65536 + (size_t)ch * 4096 +
                                qn * 1024 + f4 * 4);
    s += v.x + v.y + v.z + v.w;
    ss += v.x * v.x + v.y * v.y + v.z * v.z + v.w * v.w;
  }
#pragma unroll
  for (int off = 32; off; off >>= 1) {
    s += __shfl_xor(s, off);
    ss += __shfl_xor(ss, off);
  }
  __shared__ float rs_[4], rss_[4];
  if (lane == 0) { rs_[w] = s; rss_[w] = ss; }
  __syncthreads();
  if (t == 0) {
    stats4[(bg * 4 + qn) * 2] = rs_[0] + rs_[1] + rs_[2] + rs_[3];
    stats4[(bg * 4 + qn) * 2 + 1] = rss_[0] + rss_[1] + rss_[2] + rss_[3];
  }
}

// ---------------------------------------------------------------- groupnorm apply
__global__ __launch_bounds__(256) void gn_apply(
    const float* __restrict__ x, const float* __restrict__ gamma,
    const float* __restrict__ beta, const float* __restrict__ stats4,
    __bf16* __restrict__ h) {
  int b = blockIdx.z, g4 = blockIdx.y;
  int n = blockIdx.x * 256 + threadIdx.x;
  float mean[4], rstd[4];
#pragma unroll
  for (int k = 0; k < 4; ++k) {
    int bg = b * 32 + g4 * 4 + k;
    float s = 0.f, ss = 0.f;
#pragma unroll
    for (int q = 0; q < 4; ++q) {
      s += stats4[(bg * 4 + q) * 2];
      ss += stats4[(bg * 4 + q) * 2 + 1];
    }
    float m = s * (1.0f / 65536.0f);
    mean[k] = m;
    rstd[k] = rsqrtf(ss * (1.0f / 65536.0f) - m * m + 1e-5f);
  }
  const float* px = x + ((size_t)b * 512 + g4 * 64) * 4096 + n;
  __bf16* dst = h + ((size_t)b * 4096 + n) * 512 + g4 * 64;
#pragma unroll
  for (int j4 = 0; j4 < 8; ++j4) {
    bf16x8 o;
#pragma unroll
    for (int e = 0; e < 8; ++e) {
      int c = j4 * 8 + e;
      int g = c >> 4;
      float v = px[(size_t)c * 4096];
      o[e] = (__bf16)((v - mean[g]) * rstd[g] * gamma[g4 * 64 + c] +
                      beta[g4 * 64 + c]);
    }
    *(bf16x8*)(dst + j4 * 8) = o;
  }
}

// ---------------------------------------------------------------- gemm256<EPI>
// C[m,n] = sum_k A[m,k]*B[n,k]. 512 thr = 8 waves (2M x 4N), wave tile 128x64,
// BK=64, LDS 128 KiB dbuf, XOR(row&7) swizzle both-sides, vmcnt(4) counted waits,
// setprio around MFMA, bijective XCD swizzle. nseg>1: block covers nseg adjacent
// 256-wide N-tiles; stage() maps kt -> (seg = kt>>ktShift) B-col offset; pipeline
// runs continuously across segment boundaries with a mid-stream epilogue.
// EPI: 0 plain bf16 | 1 bf16 + 2-ptr colbias (QK fused) | 2 bf16 + rowbias (V)
//      3 f32 token-major: out[(row>>12)*512+col][row&4095] = acc+bias0[col]+resid

#define G256_PHASE(BUF, QR, QC, RDA, RDB, STAGE_STMT, TAIL_STMT)               \
  do {                                                                         \
    if (RDA) {                                                                 \
      _Pragma("unroll") for (int fr = 0; fr < 4; ++fr) {                       \
        a[fr][0] = ldA(BUF, (QR)*4 + fr, 0);                                   \
        a[fr][1] = ldA(BUF, (QR)*4 + fr, 1);                                   \
      }                                                                        \
    }                                                                          \
    if (RDB) {                                                                 \
      _Pragma("unroll") for (int fc = 0; fc < 2; ++fc) {                       \
        b[(QC)*2 + fc][0] = ldB(BUF, (QC)*2 + fc, 0);                          \
        b[(QC)*2 + fc][1] = ldB(BUF, (QC)*2 + fc, 1);                          \
      }                                                                        \
    }                                                                          \
    STAGE_STMT;                                                                \
    __builtin_amdgcn_s_barrier();                                              \
    asm volatile("s_waitcnt lgkmcnt(0)" ::: "memory");                         \
    __builtin_amdgcn_sched_barrier(0);                                         \
    __builtin_amdgcn_s_setprio(1);                                             \
    _Pragma("unroll") for (int fr = 0; fr < 4; ++fr)                           \
      _Pragma("unroll") for (int fc = 0; fc < 2; ++fc) {                       \
        acc[(QR)*4 + fr][(QC)*2 + fc] =                                        \
            __builtin_amdgcn_mfma_f32_16x16x32_bf16(                           \
                a[fr][0], b[(QC)*2 + fc][0], acc[(QR)*4 + fr][(QC)*2 + fc],    \
                0, 0, 0);                                                      \
        acc[(QR)*4 + fr][(QC)*2 + fc] =                                        \
            __builtin_amdgcn_mfma_f32_16x16x32_bf16(                           \
                a[fr][1], b[(QC)*2 + fc][1], acc[(QR)*4 + fr][(QC)*2 + fc],    \
                0, 0, 0);                                                      \
      }                                                                        \
    __builtin_amdgcn_s_setprio(0);                                             \
    TAIL_STMT;                                                                 \
    __builtin_amdgcn_sched_barrier(0);                                         \
    __builtin_amdgcn_s_barrier();                                              \
  } while (0)

#define G256_ITER(T0, T1, LAST)                                                \
  G256_PHASE(0, 0, 0, 1, 1, stage(1, 0, 0, (T1)), ((void)0));                  \
  G256_PHASE(0, 0, 1, 0, 1, stage(1, 0, 1, (T1)), ((void)0));                  \
  G256_PHASE(0, 1, 0, 1, 0,                                                    \
             if (!(LAST)) stage(0, 1, 0, (T0) + 2), ((void)0));                \
  G256_PHASE(0, 1, 1, 0, 0,                                                    \
             if (!(LAST)) stage(0, 1, 1, (T0) + 2),                            \
             if (LAST) {                                                       \
               asm volatile("s_waitcnt vmcnt(0)" ::: "memory");                \
             } else {                                                          \
               asm volatile("s_waitcnt vmcnt(4)" ::: "memory");                \
             });                                                               \
  G256_PHASE(1, 0, 0, 1, 1,                                                    \
             if (!(LAST)) stage(0, 0, 0, (T0) + 2), ((void)0));                \
  G256_PHASE(1, 0, 1, 0, 1,                                                    \
             if (!(LAST)) stage(0, 0, 1, (T0) + 2), ((void)0));                \
  G256_PHASE(1, 1, 0, 1, 0,                                                    \
             if (!(LAST)) stage(1, 1, 0, (T1) + 2), ((void)0));                \
  G256_PHASE(1, 1, 1, 0, 0,                                                    \
             if (!(LAST)) stage(1, 1, 1, (T1) + 2),                            \
             if (!(LAST)) {                                                    \
               asm volatile("s_waitcnt vmcnt(4)" ::: "memory");                \
             })

template <int EPI>
__global__ __launch_bounds__(512, 2) void gemm256(
    const __bf16* __restrict__ A, const __bf16* __restrict__ B,
    void* __restrict__ CoutV, int lda, int ldb, int ldc, int nIter, int nTM,
    int nTN, int KS, int nseg, int ktShift, long sA, long sKA, long sB,
    long sKB, long sC, const float* __restrict__ bias0,
    const float* __restrict__ bias1, const float* __restrict__ resid) {
  __shared__ __bf16 lds_raw[2][2][2][128][64];  // [buf][mat][half][row][k]

  int nwg = gridDim.x, bid = blockIdx.x;
  int qq = nwg >> 3, rr = nwg & 7;
  int xcd = bid & 7, ii = bid >> 3;
  int swz = (xcd < rr ? xcd * (qq + 1) : rr * (qq + 1) + (xcd - rr) * qq) + ii;
  int tn = swz % nTN;
  int tm = (swz / nTN) % nTM;
  int zz = swz / (nTN * nTM);
  int z = zz / KS, ks = zz % KS;
  A += (size_t)z * sA + (size_t)ks * sKA;
  B += (size_t)z * sB + (size_t)ks * sKB;
  __bf16* Cout = (__bf16*)CoutV + (size_t)zz * sC;
  int row0 = tm * 256, col0 = tn * 256 * nseg;
  int ktMask = (1 << ktShift) - 1;

  int tid = threadIdx.x;
  int wid = tid >> 6, lane = tid & 63;
  int wr = wid >> 2, wc = wid & 3;
  int l15 = lane & 15, l4 = lane >> 4;

  auto stage = [&](int buf, int mat, int half, int kt) {
    int seg = kt >> ktShift;
    int ktE = kt & ktMask;
    const __bf16* src = mat ? B : A;
    int ld = mat ? ldb : lda;
    int rbase = (mat ? col0 + seg * 256 : row0) + half * 128;
    char* ldsbase = (char*)lds_raw + (((buf * 2 + mat) * 2 + half) * 16384);
#pragma unroll
    for (int L = 0; L < 2; ++L) {
      int ci = L * 512 + tid;
      int r = ci >> 3, cslot = ci & 7;
      int csrc = cslot ^ (r & 7);
      async_copy16(src + (size_t)(rbase + r) * ld + ktE * 64 + csrc * 8,
                   ldsbase + (L * 512 + wid * 64) * 16);
    }
  };
  auto ldA = [&](int buf, int fr, int kh) -> bf16x8 {
    int row = fr * 16 + l15;
    int g = kh * 4 + l4;
    char* base = (char*)lds_raw + (((buf * 2 + 0) * 2 + wr) * 16384);
    return *(const bf16x8*)(base + row * 128 + ((g ^ (row & 7)) * 16));
  };
  auto ldB = [&](int buf, int fc, int kh) -> bf16x8 {
    int row = (wc & 1) * 64 + fc * 16 + l15;
    int g = kh * 4 + l4;
    char* base = (char*)lds_raw + (((buf * 2 + 1) * 2 + (wc >> 1)) * 16384);
    return *(const bf16x8*)(base + row * 128 + ((g ^ (row & 7)) * 16));
  };

  f32x4 acc[8][4] = {};
  bf16x8 a[4][2], b[4][2];

  // epilogue for one segment: C/D layout col=lane&15, row=(lane>>4)*4+rg
  auto wr_out = [&](int seg) {
    int rb = row0 + wr * 128, cb = col0 + seg * 256 + wc * 64;
    if constexpr (EPI == 3) {
#pragma unroll
      for (int fc = 0; fc < 4; ++fc) {
        int col = cb + fc * 16 + l15;
        float bb = bias0[col];
#pragma unroll
        for (int fr = 0; fr < 8; ++fr) {
          int r0 = rb + fr * 16 + l4 * 4;
          size_t idx = ((size_t)(r0 >> 12) * 512 + col) * 4096 + (r0 & 4095);
          float4 rv = *(const float4*)(resid + idx);
          float4 ov = {acc[fr][fc][0] + bb + rv.x, acc[fr][fc][1] + bb + rv.y,
                       acc[fr][fc][2] + bb + rv.z, acc[fr][fc][3] + bb + rv.w};
          *(float4*)((float*)CoutV + idx) = ov;
        }
      }
    } else {
#pragma unroll
      for (int fr = 0; fr < 8; ++fr) {
#pragma unroll
        for (int rg = 0; rg < 4; ++rg) {
          int row = rb + fr * 16 + l4 * 4 + rg;
#pragma unroll
          for (int fc = 0; fc < 4; ++fc) {
            int col = cb + fc * 16 + l15;
            float v = acc[fr][fc][rg];
            if constexpr (EPI == 1)
              v += col < 512 ? bias0[col] : bias1[col - 512];
            if constexpr (EPI == 2) v += bias0[row];
            Cout[(size_t)row * ldc + col] = (__bf16)v;
          }
        }
      }
    }
  };

  // prologue: buf0 {B,A} of k-tile 0, buf1 {B} of k-tile 1
  stage(0, 1, 0, 0);
  stage(0, 1, 1, 0);
  stage(0, 0, 0, 0);
  stage(0, 0, 1, 0);
  stage(1, 1, 0, 1);
  stage(1, 1, 1, 1);
  asm volatile("s_waitcnt vmcnt(4)" ::: "memory");
  __builtin_amdgcn_sched_barrier(0);
  __builtin_amdgcn_s_barrier();

  int segIters = nIter / nseg;
  int it = 0;
  for (int seg = 0; seg < nseg - 1; ++seg) {
    for (int k = 0; k < segIters; ++k, ++it) {
      G256_ITER(2 * it, 2 * it + 1, 0);
    }
    wr_out(seg);
#pragma unroll
    for (int i = 0; i < 8; ++i)
#pragma unroll
      for (int j = 0; j < 4; ++j) acc[i][j] = (f32x4){0.f, 0.f, 0.f, 0.f};
  }
  for (int k = 0; k < segIters - 1; ++k, ++it) {
    G256_ITER(2 * it, 2 * it + 1, 0);
  }
  G256_ITER(2 * it, 2 * it + 1, 1);
  wr_out(nseg - 1);
}

// ---------------------------------------------------------------- row softmax, in-place bf16 S -> bf16 P
__global__ __launch_bounds__(256) void softmax_rows_bf16(__bf16* __restrict__ S) {
  int row = blockIdx.x;
  __bf16* p = S + (size_t)row * 4096;
  int t = threadIdx.x, lane = t & 63, w = t >> 6;
  const float c1 = 0.04419417382415922f * 1.4426950408889634f;
  bf16x8 v0 = *(const bf16x8*)(p + t * 16);
  bf16x8 v1 = *(const bf16x8*)(p + t * 16 + 8);
  float f[16];
  float mx = -3.4e38f;
#pragma unroll
  for (int i = 0; i < 8; ++i) { f[i] = (float)v0[i]; mx = fmaxf(mx, f[i]); }
#pragma unroll
  for (int i = 0; i < 8; ++i) { f[8 + i] = (float)v1[i]; mx = fmaxf(mx, f[8 + i]); }
#pragma unroll
  for (int off = 32; off; off >>= 1) mx = fmaxf(mx, __shfl_xor(mx, off));
  __shared__ float rm[4], rsum[4];
  if (lane == 0) rm[w] = mx;
  __syncthreads();
  float m = fmaxf(fmaxf(rm[0], rm[1]), fmaxf(rm[2], rm[3]));
  float s = 0.f;
#pragma unroll
  for (int i = 0; i < 16; ++i) {
    f[i] = exp2f((f[i] - m) * c1);
    s += f[i];
  }
#pragma unroll
  for (int off = 32; off; off >>= 1) s += __shfl_xor(s, off);
  if (lane == 0) rsum[w] = s;
  __syncthreads();
  float inv = 1.0f / (rsum[0] + rsum[1] + rsum[2] + rsum[3]);
  bf16x8 o0, o1;
#pragma unroll
  for (int i = 0; i < 8; ++i) o0[i] = (__bf16)(f[i] * inv);
#pragma unroll
  for (int i = 0; i < 8; ++i) o1[i] = (__bf16)(f[8 + i] * inv);
  *(bf16x8*)(p + t * 16) = o0;
  *(bf16x8*)(p + t * 16 + 8) = o1;
}

// ---------------------------------------------------------------- sum 4 K-split partials -> O
__global__ __launch_bounds__(256) void reduce4(const __bf16* __restrict__ part,
                                               __bf16* __restrict__ out) {
  int z = blockIdx.y;
  size_t e = ((size_t)blockIdx.x * 256 + threadIdx.x) * 8;
  const __bf16* p = part + (size_t)z * 4 * 2097152 + e;
  bf16x8 v0 = *(const bf16x8*)(p);
  bf16x8 v1 = *(const bf16x8*)(p + 2097152);
  bf16x8 v2 = *(const bf16x8*)(p + 2 * 2097152);
  bf16x8 v3 = *(const bf16x8*)(p + 3 * 2097152);
  bf16x8 o;
#pragma unroll
  for (int j = 0; j < 8; ++j)
    o[j] = (__bf16)((float)v0[j] + (float)v1[j] + (float)v2[j] + (float)v3[j]);
  *(bf16x8*)(out + (size_t)z * 2097152 + e) = o;
}

// ---------------------------------------------------------------- launch
extern "C" void kernel_launch(void* const* d_in, const int* in_sizes, int n_in,
                              void* d_out, int out_size, void* d_ws, size_t ws_size,
                              hipStream_t stream) {
  const float* x = (const float*)d_in[0];
  const float* gamma = (const float*)d_in[1];
  const float* beta = (const float*)d_in[2];
  const float* wq = (const float*)d_in[3];
  const float* bq = (const float*)d_in[4];
  const float* wk = (const float*)d_in[5];
  const float* bk = (const float*)d_in[6];
  const float* wv = (const float*)d_in[7];
  const float* bv = (const float*)d_in[8];
  const float* wp = (const float*)d_in[9];
  const float* bp = (const float*)d_in[10];

  char* p = (char*)d_ws;
  auto alloc = [&](size_t bytes) {
    char* r = p;
    p += (bytes + 255) & ~(size_t)255;
    return r;
  };
  float* stats4 = (float*)alloc(256 * 4 * 2 * 4);
  __bf16* wqkb = (__bf16*)alloc((size_t)1024 * 512 * 2);    // [Wq; Wk]
  __bf16* wvb = (__bf16*)alloc(512 * 512 * 2);
  __bf16* wpb = (__bf16*)alloc(512 * 512 * 2);
  __bf16* ho = (__bf16*)alloc((size_t)8 * 4096 * 512 * 2);  // h, later aliased as O
  __bf16* qk = (__bf16*)alloc((size_t)8 * 4096 * 1024 * 2); // [B*N, 1024] Q|K
  __bf16* vt = (__bf16*)alloc((size_t)8 * 512 * 4096 * 2);  // [B, C, N]

  const size_t SB = (size_t)4096 * 4096 * 2;
  const size_t PB = (size_t)4 * 4096 * 512 * 2;
  size_t used = (size_t)(p - (char*)d_ws);
  size_t freeb = (ws_size > used) ? ws_size - used : 0;
  int nb = (int)(freeb / (SB + PB));
  if (nb > 8) nb = 8;
  if (nb < 1) nb = 1;
  __bf16* s = (__bf16*)alloc(SB * nb);
  __bf16* pvp = (__bf16*)alloc(PB * nb);

  cvt_w<<<512, 256, 0, stream>>>(wq, wk, wv, wp, wqkb, wqkb + 262144, wvb, wpb);
  gn_stats<<<dim3(256, 4), 256, 0, stream>>>(x, stats4);
  gn_apply<<<dim3(16, 8, 8), 256, 0, stream>>>(x, gamma, beta, stats4, ho);

  // QK fused: [32768,1024] = h x [Wq;Wk]^T + colbias2. nseg=2 -> grid 128*2 = 256
  gemm256<1><<<dim3(256), 512, 0, stream>>>(
      ho, wqkb, qk, 512, 512, 1024, 8, 128, 2, 1, 2, 3, 0, 0, 0, 0, 0,
      bq, bk, nullptr);
  // Vt[b] = Wv h[b]^T + rowbias. nseg=1, grid 256
  gemm256<2><<<dim3(256), 512, 0, stream>>>(
      wvb, ho, vt, 512, 512, 4096, 4, 2, 16, 1, 1, 10, 0, 0, 2097152, 0,
      2097152, bv, nullptr, nullptr);

  __bf16* o = ho;  // h dead after V proj -> O aliases it
  for (int b0 = 0; b0 < 8; b0 += nb) {
    int zb = (8 - b0 < nb) ? (8 - b0) : nb;
    // S = Q K^T. nseg=2 -> nTN=8, grid zb*128 (=256 at zb=2, one 1-blk/CU round)
    gemm256<0><<<dim3(zb * 128), 512, 0, stream>>>(
        qk + (size_t)b0 * 4194304, qk + (size_t)b0 * 4194304 + 512, s, 1024,
        1024, 4096, 8, 16, 8, 1, 2, 3, 4194304, 0, 4194304, 0, 16777216,
        nullptr, nullptr, nullptr);
    softmax_rows_bf16<<<zb * 4096, 256, 0, stream>>>(s);
    // partial O = P V, K-split x4: nseg=1, nIter=8, grid zb*128
    gemm256<0><<<dim3(zb * 128), 512, 0, stream>>>(
        s, vt + (size_t)b0 * 2097152, pvp, 4096, 4096, 512, 8, 16, 2, 4, 1, 10,
        16777216, 1024, 2097152, 1024, 2097152, nullptr, nullptr, nullptr);
    reduce4<<<dim3(1024, zb), 256, 0, stream>>>(pvp, o + (size_t)b0 * 2097152);
  }
  // out[b,c,n] = x + O Wp^T + bp (token-major epilogue, float4 resid+store)
  gemm256<3><<<dim3(256), 512, 0, stream>>>(
      o, wpb, d_out, 512, 512, 0, 4, 128, 2, 1, 1, 10, 0, 0, 0, 0, 0,
      bp, nullptr, x);
}

// Round 12
// 579.015 us; speedup vs baseline: 3.9505x; 1.1484x over previous
//
#include <hip/hip_runtime.h>

// AttentionBlock: GN(32) -> q,k,v 1x1 -> softmax(qk^T/sqrt(C)) v -> proj + residual
// B=8, C=512, N=4096. ALL GEMMs on gemm256 (256x256 8-phase counted-vmcnt, 8 waves,
// BK=64, T1+T2+T3+T4+T5) — round-9 structure. Round 12: QK^T tile map uses 8x8
// supertiles so each XCD's 64-block share = 2 MiB A + 2 MiB B = exactly its 4 MiB L2
// (linear map was 5 MiB -> B-panel thrash to L3).

typedef __attribute__((ext_vector_type(8))) __bf16 bf16x8;
typedef __attribute__((ext_vector_type(4))) float f32x4;
typedef unsigned int u32;

#define DEVICE __device__ __forceinline__

DEVICE void async_copy16(const void* g, void* l) {
  __builtin_amdgcn_global_load_lds(
      (__attribute__((address_space(1))) u32*)(g),
      (__attribute__((address_space(3))) u32*)(l),
      16, 0, 0);
}

// ---------------------------------------------------------------- weights->bf16
__global__ __launch_bounds__(256) void cvt_w(
    const float* __restrict__ w0, const float* __restrict__ w1,
    const float* __restrict__ w2, const float* __restrict__ w3,
    __bf16* __restrict__ o0, __bf16* __restrict__ o1,
    __bf16* __restrict__ o2, __bf16* __restrict__ o3) {
  int idx = blockIdx.x * 256 + threadIdx.x;
  int off = idx * 8;
  int m = off >> 18;
  int r = off & 262143;
  const float* src = m == 0 ? w0 : m == 1 ? w1 : m == 2 ? w2 : w3;
  __bf16* dst = m == 0 ? o0 : m == 1 ? o1 : m == 2 ? o2 : o3;
  float4 a = *(const float4*)(src + r);
  float4 b = *(const float4*)(src + r + 4);
  bf16x8 v = {(__bf16)a.x, (__bf16)a.y, (__bf16)a.z, (__bf16)a.w,
              (__bf16)b.x, (__bf16)b.y, (__bf16)b.z, (__bf16)b.w};
  *(bf16x8*)(dst + r) = v;
}

// ---------------------------------------------------------------- groupnorm partial stats
__global__ __launch_bounds__(256) void gn_stats(const float* __restrict__ x,
                                                float* __restrict__ stats4) {
  int bg = blockIdx.x, qn = blockIdx.y;
  int t = threadIdx.x, lane = t & 63, w = t >> 6;
  float s = 0.f, ss = 0.f;
  for (int it = 0; it < 16; ++it) {
    int idx = it * 256 + t;
    int ch = idx >> 8, f4 = idx & 255;
    float4 v = *(const float4*)(x + (size_t)bg * 65536 + (size_t)ch * 4096 +
                                qn * 1024 + f4 * 4);
    s += v.x + v.y + v.z + v.w;
    ss += v.x * v.x + v.y * v.y + v.z * v.z + v.w * v.w;
  }
#pragma unroll
  for (int off = 32; off; off >>= 1) {
    s += __shfl_xor(s, off);
    ss += __shfl_xor(ss, off);
  }
  __shared__ float rs_[4], rss_[4];
  if (lane == 0) { rs_[w] = s; rss_[w] = ss; }
  __syncthreads();
  if (t == 0) {
    stats4[(bg * 4 + qn) * 2] = rs_[0] + rs_[1] + rs_[2] + rs_[3];
    stats4[(bg * 4 + qn) * 2 + 1] = rss_[0] + rss_[1] + rss_[2] + rss_[3];
  }
}

// ---------------------------------------------------------------- groupnorm apply
__global__ __launch_bounds__(256) void gn_apply(
    const float* __restrict__ x, const float* __restrict__ gamma,
    const float* __restrict__ beta, const float* __restrict__ stats4,
    __bf16* __restrict__ h) {
  int b = blockIdx.z, g4 = blockIdx.y;
  int n = blockIdx.x * 256 + threadIdx.x;
  float mean[4], rstd[4];
#pragma unroll
  for (int k = 0; k < 4; ++k) {
    int bg = b * 32 + g4 * 4 + k;
    float s = 0.f, ss = 0.f;
#pragma unroll
    for (int q = 0; q < 4; ++q) {
      s += stats4[(bg * 4 + q) * 2];
      ss += stats4[(bg * 4 + q) * 2 + 1];
    }
    float m = s * (1.0f / 65536.0f);
    mean[k] = m;
    rstd[k] = rsqrtf(ss * (1.0f / 65536.0f) - m * m + 1e-5f);
  }
  const float* px = x + ((size_t)b * 512 + g4 * 64) * 4096 + n;
  __bf16* dst = h + ((size_t)b * 4096 + n) * 512 + g4 * 64;
#pragma unroll
  for (int j4 = 0; j4 < 8; ++j4) {
    bf16x8 o;
#pragma unroll
    for (int e = 0; e < 8; ++e) {
      int c = j4 * 8 + e;
      int g = c >> 4;
      float v = px[(size_t)c * 4096];
      o[e] = (__bf16)((v - mean[g]) * rstd[g] * gamma[g4 * 64 + c] +
                      beta[g4 * 64 + c]);
    }
    *(bf16x8*)(dst + j4 * 8) = o;
  }
}

// ---------------------------------------------------------------- gemm256<EPI>
// C[m,n] = sum_k A[m,k]*B[n,k]. 512 thr = 8 waves (2M x 4N), wave tile 128x64,
// BK=64, LDS 128 KiB dbuf, XOR(row&7) swizzle both-sides, vmcnt(4) counted waits,
// setprio around MFMA, bijective XCD swizzle. sup8=1: tiles mapped in 8x8
// supertiles (64 tiles) so one XCD's consecutive 64-block share is L2-resident.
// EPI: 0 plain bf16 | 1 bf16 + 2-ptr colbias (QK fused) | 2 bf16 + rowbias (V)
//      3 f32 token-major: out[(row>>12)*512+col][row&4095] = acc+bias0[col]+resid

#define G256_PHASE(BUF, QR, QC, RDA, RDB, STAGE_STMT, TAIL_STMT)               \
  do {                                                                         \
    if (RDA) {                                                                 \
      _Pragma("unroll") for (int fr = 0; fr < 4; ++fr) {                       \
        a[fr][0] = ldA(BUF, (QR)*4 + fr, 0);                                   \
        a[fr][1] = ldA(BUF, (QR)*4 + fr, 1);                                   \
      }                                                                        \
    }                                                                          \
    if (RDB) {                                                                 \
      _Pragma("unroll") for (int fc = 0; fc < 2; ++fc) {                       \
        b[(QC)*2 + fc][0] = ldB(BUF, (QC)*2 + fc, 0);                          \
        b[(QC)*2 + fc][1] = ldB(BUF, (QC)*2 + fc, 1);                          \
      }                                                                        \
    }                                                                          \
    STAGE_STMT;                                                                \
    __builtin_amdgcn_s_barrier();                                              \
    asm volatile("s_waitcnt lgkmcnt(0)" ::: "memory");                         \
    __builtin_amdgcn_sched_barrier(0);                                         \
    __builtin_amdgcn_s_setprio(1);                                             \
    _Pragma("unroll") for (int fr = 0; fr < 4; ++fr)                           \
      _Pragma("unroll") for (int fc = 0; fc < 2; ++fc) {                       \
        acc[(QR)*4 + fr][(QC)*2 + fc] =                                        \
            __builtin_amdgcn_mfma_f32_16x16x32_bf16(                           \
                a[fr][0], b[(QC)*2 + fc][0], acc[(QR)*4 + fr][(QC)*2 + fc],    \
                0, 0, 0);                                                      \
        acc[(QR)*4 + fr][(QC)*2 + fc] =                                        \
            __builtin_amdgcn_mfma_f32_16x16x32_bf16(                           \
                a[fr][1], b[(QC)*2 + fc][1], acc[(QR)*4 + fr][(QC)*2 + fc],    \
                0, 0, 0);                                                      \
      }                                                                        \
    __builtin_amdgcn_s_setprio(0);                                             \
    TAIL_STMT;                                                                 \
    __builtin_amdgcn_sched_barrier(0);                                         \
    __builtin_amdgcn_s_barrier();                                              \
  } while (0)

#define G256_ITER(T0, T1, LAST)                                                \
  G256_PHASE(0, 0, 0, 1, 1, stage(1, 0, 0, (T1)), ((void)0));                  \
  G256_PHASE(0, 0, 1, 0, 1, stage(1, 0, 1, (T1)), ((void)0));                  \
  G256_PHASE(0, 1, 0, 1, 0,                                                    \
             if (!(LAST)) stage(0, 1, 0, (T0) + 2), ((void)0));                \
  G256_PHASE(0, 1, 1, 0, 0,                                                    \
             if (!(LAST)) stage(0, 1, 1, (T0) + 2),                            \
             if (LAST) {                                                       \
               asm volatile("s_waitcnt vmcnt(0)" ::: "memory");                \
             } else {                                                          \
               asm volatile("s_waitcnt vmcnt(4)" ::: "memory");                \
             });                                                               \
  G256_PHASE(1, 0, 0, 1, 1,                                                    \
             if (!(LAST)) stage(0, 0, 0, (T0) + 2), ((void)0));                \
  G256_PHASE(1, 0, 1, 0, 1,                                                    \
             if (!(LAST)) stage(0, 0, 1, (T0) + 2), ((void)0));                \
  G256_PHASE(1, 1, 0, 1, 0,                                                    \
             if (!(LAST)) stage(1, 1, 0, (T1) + 2), ((void)0));                \
  G256_PHASE(1, 1, 1, 0, 0,                                                    \
             if (!(LAST)) stage(1, 1, 1, (T1) + 2),                            \
             if (!(LAST)) {                                                    \
               asm volatile("s_waitcnt vmcnt(4)" ::: "memory");                \
             })

template <int EPI>
__global__ __launch_bounds__(512, 2) void gemm256(
    const __bf16* __restrict__ A, const __bf16* __restrict__ B,
    void* __restrict__ CoutV, int lda, int ldb, int ldc, int nIter, int nTM,
    int nTN, int KS, int sup8, long sA, long sKA, long sB, long sKB, long sC,
    const float* __restrict__ bias0, const float* __restrict__ bias1,
    const float* __restrict__ resid) {
  __shared__ __bf16 lds_raw[2][2][2][128][64];  // [buf][mat][half][row][k]

  int nwg = gridDim.x, bid = blockIdx.x;
  int qq = nwg >> 3, rr = nwg & 7;
  int xcd = bid & 7, ii = bid >> 3;
  int swz = (xcd < rr ? xcd * (qq + 1) : rr * (qq + 1) + (xcd - rr) * qq) + ii;
  int tilesPerZ = nTM * nTN;
  int r = swz % tilesPerZ;
  int zz = swz / tilesPerZ;
  int tm, tn;
  if (sup8) {
    // 8x8 supertiles: 64 consecutive tiles = one 8-row x 8-col block
    int sup = r >> 6, local = r & 63;
    int supCols = nTN >> 3;
    tm = (sup / supCols) * 8 + (local >> 3);
    tn = (sup % supCols) * 8 + (local & 7);
  } else {
    tn = r % nTN;
    tm = r / nTN;
  }
  int z = zz / KS, ks = zz % KS;
  A += (size_t)z * sA + (size_t)ks * sKA;
  B += (size_t)z * sB + (size_t)ks * sKB;
  __bf16* Cout = (__bf16*)CoutV + (size_t)zz * sC;
  int row0 = tm * 256, col0 = tn * 256;

  int tid = threadIdx.x;
  int wid = tid >> 6, lane = tid & 63;
  int wr = wid >> 2, wc = wid & 3;
  int l15 = lane & 15, l4 = lane >> 4;

  auto stage = [&](int buf, int mat, int half, int kt) {
    const __bf16* src = mat ? B : A;
    int ld = mat ? ldb : lda;
    int rbase = (mat ? col0 : row0) + half * 128;
    char* ldsbase = (char*)lds_raw + (((buf * 2 + mat) * 2 + half) * 16384);
#pragma unroll
    for (int L = 0; L < 2; ++L) {
      int ci = L * 512 + tid;
      int rr2 = ci >> 3, cslot = ci & 7;
      int csrc = cslot ^ (rr2 & 7);
      async_copy16(src + (size_t)(rbase + rr2) * ld + kt * 64 + csrc * 8,
                   ldsbase + (L * 512 + wid * 64) * 16);
    }
  };
  auto ldA = [&](int buf, int fr, int kh) -> bf16x8 {
    int row = fr * 16 + l15;
    int g = kh * 4 + l4;
    char* base = (char*)lds_raw + (((buf * 2 + 0) * 2 + wr) * 16384);
    return *(const bf16x8*)(base + row * 128 + ((g ^ (row & 7)) * 16));
  };
  auto ldB = [&](int buf, int fc, int kh) -> bf16x8 {
    int row = (wc & 1) * 64 + fc * 16 + l15;
    int g = kh * 4 + l4;
    char* base = (char*)lds_raw + (((buf * 2 + 1) * 2 + (wc >> 1)) * 16384);
    return *(const bf16x8*)(base + row * 128 + ((g ^ (row & 7)) * 16));
  };

  f32x4 acc[8][4] = {};
  bf16x8 a[4][2], b[4][2];

  stage(0, 1, 0, 0);
  stage(0, 1, 1, 0);
  stage(0, 0, 0, 0);
  stage(0, 0, 1, 0);
  stage(1, 1, 0, 1);
  stage(1, 1, 1, 1);
  asm volatile("s_waitcnt vmcnt(4)" ::: "memory");
  __builtin_amdgcn_sched_barrier(0);
  __builtin_amdgcn_s_barrier();

  int it = 0;
  for (; it < nIter - 1; ++it) {
    G256_ITER(2 * it, 2 * it + 1, 0);
  }
  G256_ITER(2 * it, 2 * it + 1, 1);

  // epilogue: C/D layout col=lane&15, row=(lane>>4)*4+rg [m89-verified]
  int rb = row0 + wr * 128, cb = col0 + wc * 64;
  if constexpr (EPI == 3) {
#pragma unroll
    for (int fc = 0; fc < 4; ++fc) {
      int col = cb + fc * 16 + l15;
      float bb = bias0[col];
#pragma unroll
      for (int fr = 0; fr < 8; ++fr) {
        int r0 = rb + fr * 16 + l4 * 4;
        size_t idx = ((size_t)(r0 >> 12) * 512 + col) * 4096 + (r0 & 4095);
        float4 rv = *(const float4*)(resid + idx);
        float4 ov = {acc[fr][fc][0] + bb + rv.x, acc[fr][fc][1] + bb + rv.y,
                     acc[fr][fc][2] + bb + rv.z, acc[fr][fc][3] + bb + rv.w};
        *(float4*)((float*)CoutV + idx) = ov;
      }
    }
  } else {
#pragma unroll
    for (int fr = 0; fr < 8; ++fr) {
#pragma unroll
      for (int rg = 0; rg < 4; ++rg) {
        int row = rb + fr * 16 + l4 * 4 + rg;
#pragma unroll
        for (int fc = 0; fc < 4; ++fc) {
          int col = cb + fc * 16 + l15;
          float v = acc[fr][fc][rg];
          if constexpr (EPI == 1) v += col < 512 ? bias0[col] : bias1[col - 512];
          if constexpr (EPI == 2) v += bias0[row];
          Cout[(size_t)row * ldc + col] = (__bf16)v;
        }
      }
    }
  }
}

// ---------------------------------------------------------------- row softmax, in-place bf16 S -> bf16 P
__global__ __launch_bounds__(256) void softmax_rows_bf16(__bf16* __restrict__ S) {
  int row = blockIdx.x;
  __bf16* p = S + (size_t)row * 4096;
  int t = threadIdx.x, lane = t & 63, w = t >> 6;
  const float c1 = 0.04419417382415922f * 1.4426950408889634f;
  bf16x8 v0 = *(const bf16x8*)(p + t * 16);
  bf16x8 v1 = *(const bf16x8*)(p + t * 16 + 8);
  float f[16];
  float mx = -3.4e38f;
#pragma unroll
  for (int i = 0; i < 8; ++i) { f[i] = (float)v0[i]; mx = fmaxf(mx, f[i]); }
#pragma unroll
  for (int i = 0; i < 8; ++i) { f[8 + i] = (float)v1[i]; mx = fmaxf(mx, f[8 + i]); }
#pragma unroll
  for (int off = 32; off; off >>= 1) mx = fmaxf(mx, __shfl_xor(mx, off));
  __shared__ float rm[4], rsum[4];
  if (lane == 0) rm[w] = mx;
  __syncthreads();
  float m = fmaxf(fmaxf(rm[0], rm[1]), fmaxf(rm[2], rm[3]));
  float s = 0.f;
#pragma unroll
  for (int i = 0; i < 16; ++i) {
    f[i] = exp2f((f[i] - m) * c1);
    s += f[i];
  }
#pragma unroll
  for (int off = 32; off; off >>= 1) s += __shfl_xor(s, off);
  if (lane == 0) rsum[w] = s;
  __syncthreads();
  float inv = 1.0f / (rsum[0] + rsum[1] + rsum[2] + rsum[3]);
  bf16x8 o0, o1;
#pragma unroll
  for (int i = 0; i < 8; ++i) o0[i] = (__bf16)(f[i] * inv);
#pragma unroll
  for (int i = 0; i < 8; ++i) o1[i] = (__bf16)(f[8 + i] * inv);
  *(bf16x8*)(p + t * 16) = o0;
  *(bf16x8*)(p + t * 16 + 8) = o1;
}

// ---------------------------------------------------------------- sum 4 K-split partials -> O
__global__ __launch_bounds__(256) void reduce4(const __bf16* __restrict__ part,
                                               __bf16* __restrict__ out) {
  int z = blockIdx.y;
  size_t e = ((size_t)blockIdx.x * 256 + threadIdx.x) * 8;
  const __bf16* p = part + (size_t)z * 4 * 2097152 + e;
  bf16x8 v0 = *(const bf16x8*)(p);
  bf16x8 v1 = *(const bf16x8*)(p + 2097152);
  bf16x8 v2 = *(const bf16x8*)(p + 2 * 2097152);
  bf16x8 v3 = *(const bf16x8*)(p + 3 * 2097152);
  bf16x8 o;
#pragma unroll
  for (int j = 0; j < 8; ++j)
    o[j] = (__bf16)((float)v0[j] + (float)v1[j] + (float)v2[j] + (float)v3[j]);
  *(bf16x8*)(out + (size_t)z * 2097152 + e) = o;
}

// ---------------------------------------------------------------- launch
extern "C" void kernel_launch(void* const* d_in, const int* in_sizes, int n_in,
                              void* d_out, int out_size, void* d_ws, size_t ws_size,
                              hipStream_t stream) {
  const float* x = (const float*)d_in[0];
  const float* gamma = (const float*)d_in[1];
  const float* beta = (const float*)d_in[2];
  const float* wq = (const float*)d_in[3];
  const float* bq = (const float*)d_in[4];
  const float* wk = (const float*)d_in[5];
  const float* bk = (const float*)d_in[6];
  const float* wv = (const float*)d_in[7];
  const float* bv = (const float*)d_in[8];
  const float* wp = (const float*)d_in[9];
  const float* bp = (const float*)d_in[10];

  char* p = (char*)d_ws;
  auto alloc = [&](size_t bytes) {
    char* r = p;
    p += (bytes + 255) & ~(size_t)255;
    return r;
  };
  float* stats4 = (float*)alloc(256 * 4 * 2 * 4);
  __bf16* wqkb = (__bf16*)alloc((size_t)1024 * 512 * 2);    // [Wq; Wk]
  __bf16* wvb = (__bf16*)alloc(512 * 512 * 2);
  __bf16* wpb = (__bf16*)alloc(512 * 512 * 2);
  __bf16* ho = (__bf16*)alloc((size_t)8 * 4096 * 512 * 2);  // h, later aliased as O
  __bf16* qk = (__bf16*)alloc((size_t)8 * 4096 * 1024 * 2); // [B*N, 1024] Q|K
  __bf16* vt = (__bf16*)alloc((size_t)8 * 512 * 4096 * 2);  // [B, C, N]

  const size_t SB = (size_t)4096 * 4096 * 2;
  const size_t PB = (size_t)4 * 4096 * 512 * 2;
  size_t used = (size_t)(p - (char*)d_ws);
  size_t freeb = (ws_size > used) ? ws_size - used : 0;
  int nb = (int)(freeb / (SB + PB));
  if (nb > 8) nb = 8;
  if (nb < 1) nb = 1;
  __bf16* s = (__bf16*)alloc(SB * nb);
  __bf16* pvp = (__bf16*)alloc(PB * nb);

  cvt_w<<<512, 256, 0, stream>>>(wq, wk, wv, wp, wqkb, wqkb + 262144, wvb, wpb);
  gn_stats<<<dim3(256, 4), 256, 0, stream>>>(x, stats4);
  gn_apply<<<dim3(16, 8, 8), 256, 0, stream>>>(x, gamma, beta, stats4, ho);

  // QK fused: [32768,1024] = h x [Wq;Wk]^T + colbias2. grid 128*4 = 512
  gemm256<1><<<dim3(512), 512, 0, stream>>>(
      ho, wqkb, qk, 512, 512, 1024, 4, 128, 4, 1, 0, 0, 0, 0, 0, 0,
      bq, bk, nullptr);
  // Vt[b] = Wv h[b]^T + rowbias. M=512,N=4096,z=8 -> grid 256
  gemm256<2><<<dim3(256), 512, 0, stream>>>(
      wvb, ho, vt, 512, 512, 4096, 4, 2, 16, 1, 0, 0, 0, 2097152, 0, 2097152,
      bv, nullptr, nullptr);

  __bf16* o = ho;  // h dead after V proj -> O aliases it
  for (int b0 = 0; b0 < 8; b0 += nb) {
    int zb = (8 - b0 < nb) ? (8 - b0) : nb;
    // S = Q K^T. sup8=1: 8x8 supertile map -> per-XCD L2-resident panels
    gemm256<0><<<dim3(zb * 256), 512, 0, stream>>>(
        qk + (size_t)b0 * 4194304, qk + (size_t)b0 * 4194304 + 512, s, 1024,
        1024, 4096, 4, 16, 16, 1, 1, 4194304, 0, 4194304, 0, 16777216,
        nullptr, nullptr, nullptr);
    softmax_rows_bf16<<<zb * 4096, 256, 0, stream>>>(s);
    // partial O = P V, K-split x4: M=4096,N=512,Ksub=1024 -> grid zb*128
    gemm256<0><<<dim3(zb * 128), 512, 0, stream>>>(
        s, vt + (size_t)b0 * 2097152, pvp, 4096, 4096, 512, 8, 16, 2, 4, 0,
        16777216, 1024, 2097152, 1024, 2097152, nullptr, nullptr, nullptr);
    reduce4<<<dim3(1024, zb), 256, 0, stream>>>(pvp, o + (size_t)b0 * 2097152);
  }
  // out[b,c,n] = x + O Wp^T + bp (token-major epilogue, float4 resid+store)
  gemm256<3><<<dim3(256), 512, 0, stream>>>(
      o, wpb, d_out, 512, 512, 0, 4, 128, 2, 1, 0, 0, 0, 0, 0, 0,
      bp, nullptr, x);
}